// Round 19
// baseline (17.471 us; speedup 1.0000x reference)
//
#include <hip/hip_runtime.h>
#include <math.h>

// Duhamel layer == per-channel causal FIR, h[q] = (1/wD) r^q sin(q*theta).
// Exact one-stream form: e[k] = (x[k] - g^W x[k-W])/wD;  Z = g Z + e;  y = Im Z.
// r15 per-wave structure + CROSS-BLOCK PHASE OVERLAP:
//   block = (batch, 4096-chunk, channel-half): stage x window once (32 KB),
//   4 waves/block, wave w -> channel 2w+h (per-channel halo, alpha*H >= 5.1);
//   2 sub-rounds x 2048 outputs: IIR (32/lane) -> wave shfl scan -> exact
//   seed -> correct -> PRIVATE 8 KB ybuf transpose -> per-wave coalesced
//   stores.  LDS 64 KB -> 2 blocks/CU: one block's stores overlap the other
//   block's stage/compute.  512 blocks = exactly 2/CU, one generation.

#define N_SAMP  65536
#define NB      16
#define NO      8
#define NT      256           // 4 waves
#define LBLK    4096          // outputs per block per channel
#define LOOKB   3904          // ch0 halo 2048 + 1844 rounded to mult 32
#define TQ      2000          // tile quads (8000 floats = 32 KB)

constexpr int CW[NO]  = {1844, 1317, 1024, 768, 576, 419, 307, 230};
// per-lane halo samples (mult of 4): alpha*64*hseg >= 5.1 per channel
constexpr int CHS[NO] = {32, 24, 20, 16, 12, 8, 8, 4};

// XOR quad swizzle (involution within 8-quad groups): breaks stride-bank
// alignment of per-lane quad access.
__device__ __forceinline__ int P(int q) { return q ^ ((q >> 3) & 7); }

__device__ __forceinline__ float rfl(float x) {
    return __int_as_float(__builtin_amdgcn_readfirstlane(__float_as_int(x)));
}

template<int O>
__device__ __forceinline__ void duh_wave(const float* __restrict__ lw,
                                         float* __restrict__ out,
                                         const float* __restrict__ tile,
                                         float* __restrict__ yw,   // 8KB slice
                                         int b, int n0, int lane)
{
    constexpr int W  = CW[O];
    constexpr int Wu = (W + 3) & ~3;
    constexpr int E  = Wu - W;               // 0..3 intra-quad shift
    constexpr int QW = Wu / 4;               // delayed quad offset
    constexpr int HS = CHS[O];               // halo samples per lane
    constexpr int HQ = HS / 4;               // halo quads per lane

    // ---- per-wave channel constants (fast transcendentals) -> SGPR ---------
    const float omf  = fminf(fmaxf(__expf(lw[O]), 0.01f), 1000.0f);
    const float omD  = omf * 0.99874921777190895f;    // sqrt(1-0.05^2)
    const float th   = omD * 0.01f;
    const float alph = 0.0005f * omf;
    const float r1   = __expf(-alph);
    const float gr = rfl(r1 * __cosf(th)), gi = rfl(r1 * __sinf(th));   // g
    const float rW   = __expf(-alph * (float)W);
    const float aW   = th * (float)W;
    const float binv = 1.0f / omD;
    const float c1   = rfl(binv);
    const float c2   = rfl(binv * rW * __cosf(aW));    //  binv*Re g^W
    const float cei  = rfl(-binv * rW * __sinf(aW));   // -binv*Im g^W

    // G2..G4 for store correction
    float g2r_ = gr*gr - gi*gi,         g2i_ = 2.f*gr*gi;
    float g3r_ = g2r_*gr - g2i_*gi,     g3i_ = g2r_*gi + g2i_*gr;
    float g4r_ = g2r_*g2r_ - g2i_*g2i_, g4i_ = 2.f*g2r_*g2i_;
    const float G2r = rfl(g2r_), G2i = rfl(g2i_);
    const float G3r = rfl(g3r_), G3i = rfl(g3i_);
    const float G4r = rfl(g4r_), G4i = rfl(g4i_);

    // Mo[k] = g^(32*2^k) k=0..6  (out scan; Mo[6] = g^2048 carry multiplier)
    float Mor[7], Moi[7];
    {
        const float rl = __expf(-alph * 32.f);
        const float al = th * 32.f;
        float pr = rl * __cosf(al), pq = rl * __sinf(al);
#pragma unroll
        for (int k = 0; k < 7; ++k) {
            Mor[k] = rfl(pr); Moi[k] = rfl(pq);
            const float nr = pr*pr - pq*pq, ni = 2.f*pr*pq;
            pr = nr; pq = ni;
        }
    }
    // Mh[k] = g^(HS*2^k) k=0..5  (halo scan)
    float Mhr[6], Mhi[6];
    {
        const float rl = __expf(-alph * (float)HS);
        const float al = th * (float)HS;
        float pr = rl * __cosf(al), pq = rl * __sinf(al);
#pragma unroll
        for (int k = 0; k < 6; ++k) {
            Mhr[k] = rfl(pr); Mhi[k] = rfl(pq);
            const float nr = pr*pr - pq*pq, ni = 2.f*pr*pq;
            pr = nr; pq = ni;
        }
    }
    // pl = g^(32*lane)
    float plr = 1.f, pli = 0.f;
#pragma unroll
    for (int k = 0; k < 6; ++k) {
        if ((lane >> k) & 1) {
            const float nr = plr*Mor[k] - pli*Moi[k];
            const float ni = plr*Moi[k] + pli*Mor[k];
            plr = nr; pli = ni;
        }
    }

#define LDQ(q) (*(const float4*)&tile[4 * P(q)])
#define DSEL(e0,e1,e2,e3,d0,dn)                                              \
    if constexpr (E == 0)      { e0=d0.x; e1=d0.y; e2=d0.z; e3=d0.w; }       \
    else if constexpr (E == 1) { e0=d0.y; e1=d0.z; e2=d0.w; e3=dn.x; }       \
    else if constexpr (E == 2) { e0=d0.z; e1=d0.w; e2=dn.x; e3=dn.y; }       \
    else                       { e0=d0.w; e1=dn.x; e2=dn.y; e3=dn.z; }
#define STEP(xa, xc)                                              \
    {                                                             \
        const float er = fmaf(-c2, (xc), c1 * (xa));              \
        const float ei = cei * (xc);                              \
        const float nr = fmaf(gr, Br, fmaf(-gi, Bi, er));         \
        const float ni = fmaf(gi, Br, fmaf( gr, Bi, ei));         \
        Br = nr; Bi = ni;                                         \
    }

    // ---------------- halo: HS samples/lane, total only ---------------------
    float Cr, Ci;
    {
        float Br = 0.f, Bi = 0.f;
        const int q1 = 976 - 16 * HS + HQ * lane;   // covers [n0-64*HS, n0)
        const int q2 = q1 - QW;                      // >= 3 always
        float4 d0 = LDQ(q2);
#pragma unroll
        for (int m = 0; m < HQ; ++m) {
            const float4 s1 = LDQ(q1 + m);
            const float4 dn = LDQ(q2 + m + 1);
            float e0, e1, e2, e3;
            DSEL(e0, e1, e2, e3, d0, dn);
            STEP(s1.x, e0); STEP(s1.y, e1); STEP(s1.z, e2); STEP(s1.w, e3);
            d0 = dn;
        }
        float Sr = Br, Si = Bi;
#pragma unroll
        for (int k = 0; k < 6; ++k) {
            const int d = 1 << k;
            const float ur = __shfl_up(Sr, d, 64);
            const float ui = __shfl_up(Si, d, 64);
            if (lane >= d) {
                const float nr = fmaf(Mhr[k], ur, fmaf(-Mhi[k], ui, Sr));
                const float ni = fmaf(Mhr[k], ui, fmaf( Mhi[k], ur, Si));
                Sr = nr; Si = ni;
            }
        }
        Cr = rfl(__shfl(Sr, 63, 64));       // exact state at n0 (zero-seeded)
        Ci = rfl(__shfl(Si, 63, 64));
    }

    // ---------------- 2 out sub-rounds x 2048 samples -----------------------
#pragma unroll
    for (int s = 0; s < 2; ++s) {
        const int q1 = 976 + 512 * s + 8 * lane;
        const int q2 = q1 - QW;

        float4 lz[8];
        float Br = 0.f, Bi = 0.f;
        float4 d0 = LDQ(q2);
#pragma unroll
        for (int m = 0; m < 8; ++m) {
            const float4 s1 = LDQ(q1 + m);
            const float4 dn = LDQ(q2 + m + 1);
            float e0, e1, e2, e3;
            DSEL(e0, e1, e2, e3, d0, dn);
            float4 lq;
            STEP(s1.x, e0); lq.x = Bi;
            STEP(s1.y, e1); lq.y = Bi;
            STEP(s1.z, e2); lq.z = Bi;
            STEP(s1.w, e3); lq.w = Bi;
            lz[m] = lq;
            d0 = dn;
        }

        // wave inclusive affine scan (segment mult g^32)
        float Sr = Br, Si = Bi;
#pragma unroll
        for (int k = 0; k < 6; ++k) {
            const int d = 1 << k;
            const float ur = __shfl_up(Sr, d, 64);
            const float ui = __shfl_up(Si, d, 64);
            if (lane >= d) {
                const float nr = fmaf(Mor[k], ur, fmaf(-Moi[k], ui, Sr));
                const float ni = fmaf(Mor[k], ui, fmaf( Moi[k], ur, Si));
                Sr = nr; Si = ni;
            }
        }
        const float Tr = __shfl(Sr, 63, 64);
        const float Ti = __shfl(Si, 63, 64);
        float exr = __shfl_up(Sr, 1, 64);
        float exi = __shfl_up(Si, 1, 64);
        if (lane == 0) { exr = 0.f; exi = 0.f; }

        // exact seed entering this lane's 32-sample segment
        const float sr = fmaf(plr, Cr, fmaf(-pli, Ci, exr));
        const float si = fmaf(plr, Ci, fmaf( pli, Cr, exi));

        // correct + transpose through private ybuf slice (wave-local)
        float wr = fmaf(gr, sr, -(gi * si));    // w = g * seed
        float wi = fmaf(gi, sr,  (gr * si));
#pragma unroll
        for (int m = 0; m < 8; ++m) {
            float4 y;
            y.x = lz[m].x + wi;
            y.y = fmaf(gi,  wr, fmaf(gr,  wi, lz[m].y));
            y.z = fmaf(G2i, wr, fmaf(G2r, wi, lz[m].z));
            y.w = fmaf(G3i, wr, fmaf(G3r, wi, lz[m].w));
            *(float4*)&yw[4 * P(8 * lane + m)] = y;
            const float nwr = fmaf(G4r, wr, -(G4i * wi));
            const float nwi = fmaf(G4i, wr,  (G4r * wi));
            wr = nwr; wi = nwi;
        }
        // per-wave coalesced store (1 KB contiguous per instruction);
        // same-wave LDS write->read: compiler inserts the lgkmcnt wait.
        float* op = out + ((size_t)(b * NO + O)) * (size_t)N_SAMP
                        + n0 + s * 2048;
#pragma unroll
        for (int i = 0; i < 8; ++i) {
            const int q = 64 * i + lane;
            const float4 v = *(const float4*)&yw[4 * P(q)];
            *(float4*)(op + 4 * q) = v;
        }

        // carry: C = g^2048 * C + T
        const float nCr = fmaf(Mor[6], Cr, fmaf(-Moi[6], Ci, Tr));
        const float nCi = fmaf(Mor[6], Ci, fmaf( Moi[6], Cr, Ti));
        Cr = rfl(nCr); Ci = rfl(nCi);
    }
#undef STEP
#undef DSEL
#undef LDQ
}

__global__ __launch_bounds__(NT, 2)
void duh_kernel(const float* __restrict__ x, const float* __restrict__ lw,
                float* __restrict__ out)
{
    __shared__ float tile[TQ * 4];            // 32 KB
    __shared__ float ybuf[4 * 2048];          // 32 KB: 8 KB per wave
    const int c  = blockIdx.x;
    const int b  = blockIdx.y;
    const int h  = blockIdx.z;                // channel half
    const int n0 = c * LBLK;
    const int t  = threadIdx.x;

    // ---- cooperative coalesced stage: [n0-3904, n0+4096) -------------------
    const float* xb = x + (size_t)b * N_SAMP;
    const int tstart = n0 - LOOKB;
#pragma unroll
    for (int i = 0; i < 8; ++i) {
        const int k = t + 256 * i;
        if (k < TQ) {
            const int g0 = tstart + 4 * k;    // mult of 4; quad fully in/out
            float4 v;
            if (g0 >= 0) v = *(const float4*)(xb + g0);
            else { v.x = 0.f; v.y = 0.f; v.z = 0.f; v.w = 0.f; }
            *(float4*)&tile[4 * P(k)] = v;
        }
    }
    __syncthreads();                           // the ONLY block barrier

    const int wv   = t >> 6;                   // 0..3
    const int o    = 2 * wv + h;               // channels {0,2,4,6} / {1,3,5,7}
    const int lane = t & 63;
    float* yw = ybuf + wv * 2048;
    switch (o) {
      case 0: duh_wave<0>(lw, out, tile, yw, b, n0, lane); break;
      case 1: duh_wave<1>(lw, out, tile, yw, b, n0, lane); break;
      case 2: duh_wave<2>(lw, out, tile, yw, b, n0, lane); break;
      case 3: duh_wave<3>(lw, out, tile, yw, b, n0, lane); break;
      case 4: duh_wave<4>(lw, out, tile, yw, b, n0, lane); break;
      case 5: duh_wave<5>(lw, out, tile, yw, b, n0, lane); break;
      case 6: duh_wave<6>(lw, out, tile, yw, b, n0, lane); break;
      default:duh_wave<7>(lw, out, tile, yw, b, n0, lane); break;
    }
}

extern "C" void kernel_launch(void* const* d_in, const int* in_sizes, int n_in,
                              void* d_out, int out_size, void* d_ws, size_t ws_size,
                              hipStream_t stream) {
    const float* x  = (const float*)d_in[0];
    const float* lw = (const float*)d_in[1];
    float* out = (float*)d_out;

    // 16 chunks x 16 batches x 2 channel-halves = 512 blocks = 2/CU exactly
    dim3 grid(N_SAMP / LBLK, NB, 2);
    duh_kernel<<<grid, dim3(NT), 0, stream>>>(x, lw, out);
}

// Round 20
// 16.966 us; speedup vs baseline: 1.0298x; 1.0298x over previous
//
#include <hip/hip_runtime.h>
#include <math.h>

// Duhamel layer == per-channel causal FIR, h[q] = (1/wD) r^q sin(q*theta).
// Exact one-stream form: e[k] = (x[k] - g^W x[k-W])/wD;  Z = g Z + e;  y = Im Z.
// r15 structure with the two 2048-sample sub-rounds FUSED:
//   both IIR chains run in one interleaved loop (2 independent FMA chains),
//   both wave scans run in one interleaved loop (2 independent shfl chains),
//   carry seed1 = pl*(g^2048*C + T0) + ex1 needs no extra scan; corrections,
//   ybuf transposes and stores issue back-to-back at the end.
//   Geometry identical to r15: block=(batch,4096-chunk), 8 waves=8 channels,
//   32 KB tile staged once, per-channel halo, private 8 KB ybuf slices,
//   single __syncthreads, 256 blocks = 1/CU, one generation, zero tail.

#define N_SAMP  65536
#define NB      16
#define NO      8
#define NT      512
#define LBLK    4096          // outputs per block per channel
#define LOOKB   3904          // ch0 halo 2048 + 1844 rounded to mult 32
#define TQ      2000          // tile quads (8000 floats = 32 KB)

constexpr int CW[NO]  = {1844, 1317, 1024, 768, 576, 419, 307, 230};
// per-lane halo samples (mult of 4): alpha*64*hseg >= 5.1 per channel
constexpr int CHS[NO] = {32, 24, 20, 16, 12, 8, 8, 4};

// XOR quad swizzle (involution within 8-quad groups): breaks stride-bank
// alignment of per-lane quad access.
__device__ __forceinline__ int P(int q) { return q ^ ((q >> 3) & 7); }

__device__ __forceinline__ float rfl(float x) {
    return __int_as_float(__builtin_amdgcn_readfirstlane(__float_as_int(x)));
}

template<int O>
__device__ __forceinline__ void duh_wave(const float* __restrict__ lw,
                                         float* __restrict__ out,
                                         const float* __restrict__ tile,
                                         float* __restrict__ yw,   // 8KB slice
                                         int b, int n0, int lane)
{
    constexpr int W  = CW[O];
    constexpr int Wu = (W + 3) & ~3;
    constexpr int E  = Wu - W;               // 0..3 intra-quad shift
    constexpr int QW = Wu / 4;               // delayed quad offset
    constexpr int HS = CHS[O];               // halo samples per lane
    constexpr int HQ = HS / 4;               // halo quads per lane

    // ---- per-wave channel constants (fast transcendentals) -> SGPR ---------
    const float omf  = fminf(fmaxf(__expf(lw[O]), 0.01f), 1000.0f);
    const float omD  = omf * 0.99874921777190895f;    // sqrt(1-0.05^2)
    const float th   = omD * 0.01f;
    const float alph = 0.0005f * omf;
    const float r1   = __expf(-alph);
    const float gr = rfl(r1 * __cosf(th)), gi = rfl(r1 * __sinf(th));   // g
    const float rW   = __expf(-alph * (float)W);
    const float aW   = th * (float)W;
    const float binv = 1.0f / omD;
    const float c1   = rfl(binv);
    const float c2   = rfl(binv * rW * __cosf(aW));    //  binv*Re g^W
    const float cei  = rfl(-binv * rW * __sinf(aW));   // -binv*Im g^W

    // G2..G4 for store correction
    float g2r_ = gr*gr - gi*gi,         g2i_ = 2.f*gr*gi;
    float g3r_ = g2r_*gr - g2i_*gi,     g3i_ = g2r_*gi + g2i_*gr;
    float g4r_ = g2r_*g2r_ - g2i_*g2i_, g4i_ = 2.f*g2r_*g2i_;
    const float G2r = rfl(g2r_), G2i = rfl(g2i_);
    const float G3r = rfl(g3r_), G3i = rfl(g3i_);
    const float G4r = rfl(g4r_), G4i = rfl(g4i_);

    // Mo[k] = g^(32*2^k) k=0..6  (out scan; Mo[6] = g^2048 carry multiplier)
    float Mor[7], Moi[7];
    {
        const float rl = __expf(-alph * 32.f);
        const float al = th * 32.f;
        float pr = rl * __cosf(al), pq = rl * __sinf(al);
#pragma unroll
        for (int k = 0; k < 7; ++k) {
            Mor[k] = rfl(pr); Moi[k] = rfl(pq);
            const float nr = pr*pr - pq*pq, ni = 2.f*pr*pq;
            pr = nr; pq = ni;
        }
    }
    // Mh[k] = g^(HS*2^k) k=0..5  (halo scan)
    float Mhr[6], Mhi[6];
    {
        const float rl = __expf(-alph * (float)HS);
        const float al = th * (float)HS;
        float pr = rl * __cosf(al), pq = rl * __sinf(al);
#pragma unroll
        for (int k = 0; k < 6; ++k) {
            Mhr[k] = rfl(pr); Mhi[k] = rfl(pq);
            const float nr = pr*pr - pq*pq, ni = 2.f*pr*pq;
            pr = nr; pq = ni;
        }
    }
    // pl = g^(32*lane)
    float plr = 1.f, pli = 0.f;
#pragma unroll
    for (int k = 0; k < 6; ++k) {
        if ((lane >> k) & 1) {
            const float nr = plr*Mor[k] - pli*Moi[k];
            const float ni = plr*Moi[k] + pli*Mor[k];
            plr = nr; pli = ni;
        }
    }

#define LDQ(q) (*(const float4*)&tile[4 * P(q)])
#define DSEL(e0,e1,e2,e3,d0,dn)                                              \
    if constexpr (E == 0)      { e0=d0.x; e1=d0.y; e2=d0.z; e3=d0.w; }       \
    else if constexpr (E == 1) { e0=d0.y; e1=d0.z; e2=d0.w; e3=dn.x; }       \
    else if constexpr (E == 2) { e0=d0.z; e1=d0.w; e2=dn.x; e3=dn.y; }       \
    else                       { e0=d0.w; e1=dn.x; e2=dn.y; e3=dn.z; }
#define STEPV(Br, Bi, xa, xc)                                     \
    {                                                             \
        const float er = fmaf(-c2, (xc), c1 * (xa));              \
        const float ei = cei * (xc);                              \
        const float nr = fmaf(gr, Br, fmaf(-gi, Bi, er));         \
        const float ni = fmaf(gi, Br, fmaf( gr, Bi, ei));         \
        Br = nr; Bi = ni;                                         \
    }

    // ---------------- halo: HS samples/lane, total only ---------------------
    float Cr, Ci;
    {
        float Br = 0.f, Bi = 0.f;
        const int q1 = 976 - 16 * HS + HQ * lane;   // covers [n0-64*HS, n0)
        const int q2 = q1 - QW;                      // >= 3 always
        float4 d0 = LDQ(q2);
#pragma unroll
        for (int m = 0; m < HQ; ++m) {
            const float4 s1 = LDQ(q1 + m);
            const float4 dn = LDQ(q2 + m + 1);
            float e0, e1, e2, e3;
            DSEL(e0, e1, e2, e3, d0, dn);
            STEPV(Br, Bi, s1.x, e0); STEPV(Br, Bi, s1.y, e1);
            STEPV(Br, Bi, s1.z, e2); STEPV(Br, Bi, s1.w, e3);
            d0 = dn;
        }
        float Sr = Br, Si = Bi;
#pragma unroll
        for (int k = 0; k < 6; ++k) {
            const int d = 1 << k;
            const float ur = __shfl_up(Sr, d, 64);
            const float ui = __shfl_up(Si, d, 64);
            if (lane >= d) {
                const float nr = fmaf(Mhr[k], ur, fmaf(-Mhi[k], ui, Sr));
                const float ni = fmaf(Mhr[k], ui, fmaf( Mhi[k], ur, Si));
                Sr = nr; Si = ni;
            }
        }
        Cr = rfl(__shfl(Sr, 63, 64));       // exact state at n0 (zero-seeded)
        Ci = rfl(__shfl(Si, 63, 64));
    }

    // ---------------- fused IIR: both 2048-sample sub-rounds ---------------
    const int qa = 976 + 8 * lane;          // sub-round 0 own-quad base
    const int qb = qa + 512;                // sub-round 1 own-quad base

    float4 lz0[8], lz1[8];
    float B0r = 0.f, B0i = 0.f, B1r = 0.f, B1i = 0.f;
    {
        float4 d0a = LDQ(qa - QW);
        float4 d0b = LDQ(qb - QW);
#pragma unroll
        for (int m = 0; m < 8; ++m) {
            const float4 s1a = LDQ(qa + m);
            const float4 dna = LDQ(qa - QW + m + 1);
            const float4 s1b = LDQ(qb + m);
            const float4 dnb = LDQ(qb - QW + m + 1);
            float a0, a1, a2, a3, b0, b1, b2, b3;
            DSEL(a0, a1, a2, a3, d0a, dna);
            DSEL(b0, b1, b2, b3, d0b, dnb);
            float4 l0, l1;
            STEPV(B0r, B0i, s1a.x, a0); l0.x = B0i;
            STEPV(B1r, B1i, s1b.x, b0); l1.x = B1i;
            STEPV(B0r, B0i, s1a.y, a1); l0.y = B0i;
            STEPV(B1r, B1i, s1b.y, b1); l1.y = B1i;
            STEPV(B0r, B0i, s1a.z, a2); l0.z = B0i;
            STEPV(B1r, B1i, s1b.z, b2); l1.z = B1i;
            STEPV(B0r, B0i, s1a.w, a3); l0.w = B0i;
            STEPV(B1r, B1i, s1b.w, b3); l1.w = B1i;
            lz0[m] = l0; lz1[m] = l1;
            d0a = dna; d0b = dnb;
        }
    }

    // ---------------- fused wave scans (two independent shfl chains) --------
    float S0r = B0r, S0i = B0i, S1r = B1r, S1i = B1i;
#pragma unroll
    for (int k = 0; k < 6; ++k) {
        const int d = 1 << k;
        const float u0r = __shfl_up(S0r, d, 64);
        const float u0i = __shfl_up(S0i, d, 64);
        const float u1r = __shfl_up(S1r, d, 64);
        const float u1i = __shfl_up(S1i, d, 64);
        if (lane >= d) {
            const float n0r = fmaf(Mor[k], u0r, fmaf(-Moi[k], u0i, S0r));
            const float n0i = fmaf(Mor[k], u0i, fmaf( Moi[k], u0r, S0i));
            const float n1r = fmaf(Mor[k], u1r, fmaf(-Moi[k], u1i, S1r));
            const float n1i = fmaf(Mor[k], u1i, fmaf( Moi[k], u1r, S1i));
            S0r = n0r; S0i = n0i; S1r = n1r; S1i = n1i;
        }
    }
    const float T0r = __shfl(S0r, 63, 64);
    const float T0i = __shfl(S0i, 63, 64);
    float ex0r = __shfl_up(S0r, 1, 64);
    float ex0i = __shfl_up(S0i, 1, 64);
    float ex1r = __shfl_up(S1r, 1, 64);
    float ex1i = __shfl_up(S1i, 1, 64);
    if (lane == 0) { ex0r = 0.f; ex0i = 0.f; ex1r = 0.f; ex1i = 0.f; }

    // seeds: seed0 = pl*C + ex0;  C1 = g^2048*C + T0;  seed1 = pl*C1 + ex1
    const float s0r = fmaf(plr, Cr, fmaf(-pli, Ci, ex0r));
    const float s0i = fmaf(plr, Ci, fmaf( pli, Cr, ex0i));
    const float C1r = rfl(fmaf(Mor[6], Cr, fmaf(-Moi[6], Ci, T0r)));
    const float C1i = rfl(fmaf(Mor[6], Ci, fmaf( Moi[6], Cr, T0i)));
    const float s1r = fmaf(plr, C1r, fmaf(-pli, C1i, ex1r));
    const float s1i = fmaf(plr, C1i, fmaf( pli, C1r, ex1i));

    // ---------------- corrections + ybuf transposes + stores ----------------
    float* opb = out + ((size_t)(b * NO + O)) * (size_t)N_SAMP + n0;
#pragma unroll
    for (int s = 0; s < 2; ++s) {
        const float sr = (s == 0) ? s0r : s1r;
        const float si = (s == 0) ? s0i : s1i;
        float wr = fmaf(gr, sr, -(gi * si));    // w = g * seed
        float wi = fmaf(gi, sr,  (gr * si));
#pragma unroll
        for (int m = 0; m < 8; ++m) {
            const float4 z = (s == 0) ? lz0[m] : lz1[m];
            float4 y;
            y.x = z.x + wi;
            y.y = fmaf(gi,  wr, fmaf(gr,  wi, z.y));
            y.z = fmaf(G2i, wr, fmaf(G2r, wi, z.z));
            y.w = fmaf(G3i, wr, fmaf(G3r, wi, z.w));
            *(float4*)&yw[4 * P(8 * lane + m)] = y;
            const float nwr = fmaf(G4r, wr, -(G4i * wi));
            const float nwi = fmaf(G4i, wr,  (G4r * wi));
            wr = nwr; wi = nwi;
        }
        // per-wave coalesced store (1 KB contiguous per instruction);
        // same-wave LDS write->read ordering handled by lgkmcnt.
        float* op = opb + s * 2048;
#pragma unroll
        for (int i = 0; i < 8; ++i) {
            const int q = 64 * i + lane;
            const float4 v = *(const float4*)&yw[4 * P(q)];
            *(float4*)(op + 4 * q) = v;
        }
    }
#undef STEPV
#undef DSEL
#undef LDQ
}

__global__ __launch_bounds__(NT, 2)
void duh_kernel(const float* __restrict__ x, const float* __restrict__ lw,
                float* __restrict__ out)
{
    __shared__ float tile[TQ * 4];            // 32 KB
    __shared__ float ybuf[NO * 2048];         // 64 KB: 8 KB per wave
    const int c  = blockIdx.x;
    const int b  = blockIdx.y;
    const int n0 = c * LBLK;
    const int t  = threadIdx.x;

    // ---- cooperative coalesced stage: [n0-3904, n0+4096) -------------------
    const float* xb = x + (size_t)b * N_SAMP;
    const int tstart = n0 - LOOKB;
#pragma unroll
    for (int i = 0; i < 4; ++i) {
        const int k = t + 512 * i;
        if (k < TQ) {
            const int g0 = tstart + 4 * k;    // mult of 4; quad fully in/out
            float4 v;
            if (g0 >= 0) v = *(const float4*)(xb + g0);
            else { v.x = 0.f; v.y = 0.f; v.z = 0.f; v.w = 0.f; }
            *(float4*)&tile[4 * P(k)] = v;
        }
    }
    __syncthreads();                           // the ONLY block barrier

    const int wv   = t >> 6;
    const int lane = t & 63;
    float* yw = ybuf + wv * 2048;
    switch (wv) {                              // wave o <-> channel o
      case 0: duh_wave<0>(lw, out, tile, yw, b, n0, lane); break;
      case 1: duh_wave<1>(lw, out, tile, yw, b, n0, lane); break;
      case 2: duh_wave<2>(lw, out, tile, yw, b, n0, lane); break;
      case 3: duh_wave<3>(lw, out, tile, yw, b, n0, lane); break;
      case 4: duh_wave<4>(lw, out, tile, yw, b, n0, lane); break;
      case 5: duh_wave<5>(lw, out, tile, yw, b, n0, lane); break;
      case 6: duh_wave<6>(lw, out, tile, yw, b, n0, lane); break;
      default:duh_wave<7>(lw, out, tile, yw, b, n0, lane); break;
    }
}

extern "C" void kernel_launch(void* const* d_in, const int* in_sizes, int n_in,
                              void* d_out, int out_size, void* d_ws, size_t ws_size,
                              hipStream_t stream) {
    const float* x  = (const float*)d_in[0];
    const float* lw = (const float*)d_in[1];
    float* out = (float*)d_out;

    dim3 grid(N_SAMP / LBLK, NB);   // 16 chunks x 16 batches = 256 blocks
    duh_kernel<<<grid, dim3(NT), 0, stream>>>(x, lw, out);
}

// Round 21
// 16.690 us; speedup vs baseline: 1.0468x; 1.0165x over previous
//
#include <hip/hip_runtime.h>
#include <math.h>

// Duhamel layer == per-channel causal FIR, h[q] = (1/wD) r^q sin(q*theta).
// Exact one-stream form: e[k] = (x[k] - g^W x[k-W])/wD;  Z = g Z + e;  y = Im Z.
// FINAL (r15 = best measured, 16.48 us):
// ALL-CHANNELS-ONE-STAGE + WAVE-AUTONOMOUS STORES:
//   block = (batch, 4096-chunk): stage x window ONCE (32 KB, swizzled);
//   wave o = channel o with per-channel halo (alpha*H >= 5.1);
//   2 sub-rounds x 2048 outputs: IIR (32/lane, lz in regs) -> wave shfl scan
//   -> exact seed -> correction fused -> transpose via PRIVATE 8 KB ybuf
//   slice (wave-local, no block barrier) -> per-wave coalesced 1 KB stores.
//   Single __syncthreads (after stage).  256 blocks = 1/CU, one generation.

#define N_SAMP  65536
#define NB      16
#define NO      8
#define NT      512
#define LBLK    4096          // outputs per block per channel
#define LOOKB   3904          // ch0 halo 2048 + 1844 rounded to mult 32
#define TQ      2000          // tile quads (8000 floats = 32 KB)

constexpr int CW[NO]  = {1844, 1317, 1024, 768, 576, 419, 307, 230};
// per-lane halo samples (mult of 4): alpha*64*hseg >= 5.1 per channel
constexpr int CHS[NO] = {32, 24, 20, 16, 12, 8, 8, 4};

// XOR quad swizzle (involution within 8-quad groups): breaks stride-bank
// alignment of per-lane quad access.
__device__ __forceinline__ int P(int q) { return q ^ ((q >> 3) & 7); }

__device__ __forceinline__ float rfl(float x) {
    return __int_as_float(__builtin_amdgcn_readfirstlane(__float_as_int(x)));
}

template<int O>
__device__ __forceinline__ void duh_wave(const float* __restrict__ lw,
                                         float* __restrict__ out,
                                         const float* __restrict__ tile,
                                         float* __restrict__ yw,   // 8KB slice
                                         int b, int n0, int lane)
{
    constexpr int W  = CW[O];
    constexpr int Wu = (W + 3) & ~3;
    constexpr int E  = Wu - W;               // 0..3 intra-quad shift
    constexpr int QW = Wu / 4;               // delayed quad offset
    constexpr int HS = CHS[O];               // halo samples per lane
    constexpr int HQ = HS / 4;               // halo quads per lane

    // ---- per-wave channel constants (fast transcendentals) -> SGPR ---------
    const float omf  = fminf(fmaxf(__expf(lw[O]), 0.01f), 1000.0f);
    const float omD  = omf * 0.99874921777190895f;    // sqrt(1-0.05^2)
    const float th   = omD * 0.01f;
    const float alph = 0.0005f * omf;
    const float r1   = __expf(-alph);
    const float gr = rfl(r1 * __cosf(th)), gi = rfl(r1 * __sinf(th));   // g
    const float rW   = __expf(-alph * (float)W);
    const float aW   = th * (float)W;
    const float binv = 1.0f / omD;
    const float c1   = rfl(binv);
    const float c2   = rfl(binv * rW * __cosf(aW));    //  binv*Re g^W
    const float cei  = rfl(-binv * rW * __sinf(aW));   // -binv*Im g^W

    // G2..G4 for store correction
    float g2r_ = gr*gr - gi*gi,         g2i_ = 2.f*gr*gi;
    float g3r_ = g2r_*gr - g2i_*gi,     g3i_ = g2r_*gi + g2i_*gr;
    float g4r_ = g2r_*g2r_ - g2i_*g2i_, g4i_ = 2.f*g2r_*g2i_;
    const float G2r = rfl(g2r_), G2i = rfl(g2i_);
    const float G3r = rfl(g3r_), G3i = rfl(g3i_);
    const float G4r = rfl(g4r_), G4i = rfl(g4i_);

    // Mo[k] = g^(32*2^k) k=0..6  (out scan; Mo[6] = g^2048 carry multiplier)
    float Mor[7], Moi[7];
    {
        const float rl = __expf(-alph * 32.f);
        const float al = th * 32.f;
        float pr = rl * __cosf(al), pq = rl * __sinf(al);
#pragma unroll
        for (int k = 0; k < 7; ++k) {
            Mor[k] = rfl(pr); Moi[k] = rfl(pq);
            const float nr = pr*pr - pq*pq, ni = 2.f*pr*pq;
            pr = nr; pq = ni;
        }
    }
    // Mh[k] = g^(HS*2^k) k=0..5  (halo scan)
    float Mhr[6], Mhi[6];
    {
        const float rl = __expf(-alph * (float)HS);
        const float al = th * (float)HS;
        float pr = rl * __cosf(al), pq = rl * __sinf(al);
#pragma unroll
        for (int k = 0; k < 6; ++k) {
            Mhr[k] = rfl(pr); Mhi[k] = rfl(pq);
            const float nr = pr*pr - pq*pq, ni = 2.f*pr*pq;
            pr = nr; pq = ni;
        }
    }
    // pl = g^(32*lane)
    float plr = 1.f, pli = 0.f;
#pragma unroll
    for (int k = 0; k < 6; ++k) {
        if ((lane >> k) & 1) {
            const float nr = plr*Mor[k] - pli*Moi[k];
            const float ni = plr*Moi[k] + pli*Mor[k];
            plr = nr; pli = ni;
        }
    }

#define LDQ(q) (*(const float4*)&tile[4 * P(q)])
#define DSEL(e0,e1,e2,e3,d0,dn)                                              \
    if constexpr (E == 0)      { e0=d0.x; e1=d0.y; e2=d0.z; e3=d0.w; }       \
    else if constexpr (E == 1) { e0=d0.y; e1=d0.z; e2=d0.w; e3=dn.x; }       \
    else if constexpr (E == 2) { e0=d0.z; e1=d0.w; e2=dn.x; e3=dn.y; }       \
    else                       { e0=d0.w; e1=dn.x; e2=dn.y; e3=dn.z; }
#define STEP(xa, xc)                                              \
    {                                                             \
        const float er = fmaf(-c2, (xc), c1 * (xa));              \
        const float ei = cei * (xc);                              \
        const float nr = fmaf(gr, Br, fmaf(-gi, Bi, er));         \
        const float ni = fmaf(gi, Br, fmaf( gr, Bi, ei));         \
        Br = nr; Bi = ni;                                         \
    }

    // ---------------- halo: HS samples/lane, total only ---------------------
    float Cr, Ci;
    {
        float Br = 0.f, Bi = 0.f;
        const int q1 = 976 - 16 * HS + HQ * lane;   // covers [n0-64*HS, n0)
        const int q2 = q1 - QW;
        float4 d0 = LDQ(q2);
#pragma unroll
        for (int m = 0; m < HQ; ++m) {
            const float4 s1 = LDQ(q1 + m);
            const float4 dn = LDQ(q2 + m + 1);
            float e0, e1, e2, e3;
            DSEL(e0, e1, e2, e3, d0, dn);
            STEP(s1.x, e0); STEP(s1.y, e1); STEP(s1.z, e2); STEP(s1.w, e3);
            d0 = dn;
        }
        float Sr = Br, Si = Bi;
#pragma unroll
        for (int k = 0; k < 6; ++k) {
            const int d = 1 << k;
            const float ur = __shfl_up(Sr, d, 64);
            const float ui = __shfl_up(Si, d, 64);
            if (lane >= d) {
                const float nr = fmaf(Mhr[k], ur, fmaf(-Mhi[k], ui, Sr));
                const float ni = fmaf(Mhr[k], ui, fmaf( Mhi[k], ur, Si));
                Sr = nr; Si = ni;
            }
        }
        Cr = rfl(__shfl(Sr, 63, 64));       // exact state at n0 (zero-seeded)
        Ci = rfl(__shfl(Si, 63, 64));
    }

    // ---------------- 2 out sub-rounds x 2048 samples -----------------------
#pragma unroll
    for (int s = 0; s < 2; ++s) {
        const int q1 = 976 + 512 * s + 8 * lane;
        const int q2 = q1 - QW;

        float4 lz[8];
        float Br = 0.f, Bi = 0.f;
        float4 d0 = LDQ(q2);
#pragma unroll
        for (int m = 0; m < 8; ++m) {
            const float4 s1 = LDQ(q1 + m);
            const float4 dn = LDQ(q2 + m + 1);
            float e0, e1, e2, e3;
            DSEL(e0, e1, e2, e3, d0, dn);
            float4 lq;
            STEP(s1.x, e0); lq.x = Bi;
            STEP(s1.y, e1); lq.y = Bi;
            STEP(s1.z, e2); lq.z = Bi;
            STEP(s1.w, e3); lq.w = Bi;
            lz[m] = lq;
            d0 = dn;
        }

        // wave inclusive affine scan (segment mult g^32)
        float Sr = Br, Si = Bi;
#pragma unroll
        for (int k = 0; k < 6; ++k) {
            const int d = 1 << k;
            const float ur = __shfl_up(Sr, d, 64);
            const float ui = __shfl_up(Si, d, 64);
            if (lane >= d) {
                const float nr = fmaf(Mor[k], ur, fmaf(-Moi[k], ui, Sr));
                const float ni = fmaf(Mor[k], ui, fmaf( Moi[k], ur, Si));
                Sr = nr; Si = ni;
            }
        }
        const float Tr = __shfl(Sr, 63, 64);
        const float Ti = __shfl(Si, 63, 64);
        float exr = __shfl_up(Sr, 1, 64);
        float exi = __shfl_up(Si, 1, 64);
        if (lane == 0) { exr = 0.f; exi = 0.f; }

        // exact seed entering this lane's 32-sample segment
        const float sr = fmaf(plr, Cr, fmaf(-pli, Ci, exr));
        const float si = fmaf(plr, Ci, fmaf( pli, Cr, exi));

        // correct + transpose through private ybuf slice (wave-local)
        float wr = fmaf(gr, sr, -(gi * si));    // w = g * seed
        float wi = fmaf(gi, sr,  (gr * si));
#pragma unroll
        for (int m = 0; m < 8; ++m) {
            float4 y;
            y.x = lz[m].x + wi;
            y.y = fmaf(gi,  wr, fmaf(gr,  wi, lz[m].y));
            y.z = fmaf(G2i, wr, fmaf(G2r, wi, lz[m].z));
            y.w = fmaf(G3i, wr, fmaf(G3r, wi, lz[m].w));
            *(float4*)&yw[4 * P(8 * lane + m)] = y;
            const float nwr = fmaf(G4r, wr, -(G4i * wi));
            const float nwi = fmaf(G4i, wr,  (G4r * wi));
            wr = nwr; wi = nwi;
        }
        // per-wave coalesced store (1 KB contiguous per instruction);
        // same-wave LDS write->read: compiler inserts the lgkmcnt wait.
        float* op = out + ((size_t)(b * NO + O)) * (size_t)N_SAMP
                        + n0 + s * 2048;
#pragma unroll
        for (int i = 0; i < 8; ++i) {
            const int q = 64 * i + lane;
            const float4 v = *(const float4*)&yw[4 * P(q)];
            *(float4*)(op + 4 * q) = v;
        }

        // carry: C = g^2048 * C + T
        const float nCr = fmaf(Mor[6], Cr, fmaf(-Moi[6], Ci, Tr));
        const float nCi = fmaf(Mor[6], Ci, fmaf( Moi[6], Cr, Ti));
        Cr = rfl(nCr); Ci = rfl(nCi);
    }
#undef STEP
#undef DSEL
#undef LDQ
}

__global__ __launch_bounds__(NT, 2)
void duh_kernel(const float* __restrict__ x, const float* __restrict__ lw,
                float* __restrict__ out)
{
    __shared__ float tile[TQ * 4];            // 32 KB
    __shared__ float ybuf[NO * 2048];         // 64 KB: 8 KB per wave
    const int c  = blockIdx.x;
    const int b  = blockIdx.y;
    const int n0 = c * LBLK;
    const int t  = threadIdx.x;

    // ---- cooperative coalesced stage: [n0-3904, n0+4096) -------------------
    const float* xb = x + (size_t)b * N_SAMP;
    const int tstart = n0 - LOOKB;
#pragma unroll
    for (int i = 0; i < 4; ++i) {
        const int k = t + 512 * i;
        if (k < TQ) {
            const int g0 = tstart + 4 * k;    // mult of 4; quad fully in/out
            float4 v;
            if (g0 >= 0) v = *(const float4*)(xb + g0);
            else { v.x = 0.f; v.y = 0.f; v.z = 0.f; v.w = 0.f; }
            *(float4*)&tile[4 * P(k)] = v;
        }
    }
    __syncthreads();                           // the ONLY block barrier

    const int wv   = t >> 6;
    const int lane = t & 63;
    float* yw = ybuf + wv * 2048;
    switch (wv) {                              // wave o <-> channel o
      case 0: duh_wave<0>(lw, out, tile, yw, b, n0, lane); break;
      case 1: duh_wave<1>(lw, out, tile, yw, b, n0, lane); break;
      case 2: duh_wave<2>(lw, out, tile, yw, b, n0, lane); break;
      case 3: duh_wave<3>(lw, out, tile, yw, b, n0, lane); break;
      case 4: duh_wave<4>(lw, out, tile, yw, b, n0, lane); break;
      case 5: duh_wave<5>(lw, out, tile, yw, b, n0, lane); break;
      case 6: duh_wave<6>(lw, out, tile, yw, b, n0, lane); break;
      default:duh_wave<7>(lw, out, tile, yw, b, n0, lane); break;
    }
}

extern "C" void kernel_launch(void* const* d_in, const int* in_sizes, int n_in,
                              void* d_out, int out_size, void* d_ws, size_t ws_size,
                              hipStream_t stream) {
    const float* x  = (const float*)d_in[0];
    const float* lw = (const float*)d_in[1];
    float* out = (float*)d_out;

    dim3 grid(N_SAMP / LBLK, NB);   // 16 chunks x 16 batches = 256 blocks
    duh_kernel<<<grid, dim3(NT), 0, stream>>>(x, lw, out);
}